// Round 13
// baseline (300.654 us; speedup 1.0000x reference)
//
#include <hip/hip_runtime.h>
#include <math.h>

static constexpr int HEADS = 2;

typedef unsigned int u32;
typedef __attribute__((ext_vector_type(4))) short short4v;
typedef __attribute__((ext_vector_type(8))) short short8v;
typedef __attribute__((ext_vector_type(4))) float f32x4;
typedef __attribute__((ext_vector_type(2))) float f32x2;

__device__ __forceinline__ unsigned short f2b(float f) {
  union { float f; u32 u; } v; v.f = f;
  u32 u = v.u;
  u32 r = (u + 0x7fffu + ((u >> 16) & 1u)) >> 16;  // RNE
  return (unsigned short)r;
}
__device__ __forceinline__ float b2f(unsigned short b) {
  union { u32 u; float f; } v; v.u = ((u32)b) << 16;
  return v.f;
}
// unpack u32 holding 2 bf16 -> f32x2 {lo, hi}
__device__ __forceinline__ f32x2 bpair(u32 u) {
  union { u32 u; float f; } a, b;
  a.u = u << 16; b.u = u & 0xffff0000u;
  f32x2 r; r.x = a.f; r.y = b.f; return r;
}

// packed fp32 VOP3P ops (gfx90a+)
__device__ __forceinline__ f32x2 pk_add(f32x2 a, f32x2 b) {
  f32x2 d; asm("v_pk_add_f32 %0, %1, %2" : "=v"(d) : "v"(a), "v"(b)); return d;
}
__device__ __forceinline__ f32x2 pk_fma(f32x2 a, f32x2 b, f32x2 c) {
  f32x2 d; asm("v_pk_fma_f32 %0, %1, %2, %3" : "=v"(d) : "v"(a), "v"(b), "v"(c)); return d;
}
__device__ __forceinline__ f32x2 pk_abs(f32x2 a) {
  union { f32x2 f; u32 u[2]; } v; v.f = a;
  v.u[0] &= 0x7fffffffu; v.u[1] &= 0x7fffffffu; return v.f;
}

__device__ __forceinline__ void async_copy16(const void* g, void* l) {
  __builtin_amdgcn_global_load_lds(
      (const __attribute__((address_space(1))) u32*)g,
      (__attribute__((address_space(3))) u32*)l, 16, 0, 0);
}

// ---------------- CSR build + degree sort ----------------
__global__ void k_count(const int* __restrict__ dst, int* __restrict__ deg, int E) {
  int t = blockIdx.x * blockDim.x + threadIdx.x;
  if (t < E) atomicAdd(&deg[dst[t]], 1);
}

// parallel degree histogram: per-block LDS hist, one global atomic/bin/block
__global__ __launch_bounds__(256) void k_hist(const int* __restrict__ deg,
                                              int* __restrict__ hist, int n) {
  __shared__ int lh[256];
  int t = threadIdx.x;
  lh[t] = 0;
  __syncthreads();
  for (int i = blockIdx.x * 256 + t; i < n; i += gridDim.x * 256) {
    int d = deg[i]; d = d > 255 ? 255 : d;
    atomicAdd(&lh[d], 1);
  }
  __syncthreads();
  if (lh[t]) atomicAdd(&hist[t], lh[t]);
}

// offsets scan + dbase from precomputed hist
__global__ void k_scan(const int* __restrict__ deg, int* __restrict__ off,
                       const int* __restrict__ hist, int* __restrict__ dbase, int n) {
  __shared__ int part[1024];
  int t = threadIdx.x;
  int per = (n + 1023) >> 10;
  int s0 = t * per, s1 = min(s0 + per, n);
  int s = 0;
  for (int i = s0; i < s1; ++i) s += deg[i];
  part[t] = s;
  __syncthreads();
  if (t == 0) {  // suffix sum: dbase[d] = #nodes with degree > d (descending order)
    int run = 0;
    for (int d = 255; d >= 0; --d) { dbase[d] = run; run += hist[d]; }
  }
  for (int d = 1; d < 1024; d <<= 1) {
    int v = (t >= d) ? part[t - d] : 0;
    __syncthreads();
    part[t] += v;
    __syncthreads();
  }
  int base = (t == 0) ? 0 : part[t - 1];
  for (int i = s0; i < s1; ++i) { off[i] = base; base += deg[i]; }
  if (t == 1023) off[n] = part[1023];
}

__global__ void k_place(const int* __restrict__ deg, const int* __restrict__ dbase,
                        int* __restrict__ dcur, int* __restrict__ order, int n) {
  int i = blockIdx.x * blockDim.x + threadIdx.x;
  if (i < n) {
    int d = deg[i]; d = d > 255 ? 255 : d;
    int pos = dbase[d] + atomicAdd(&dcur[d], 1);
    order[pos] = i;
  }
}

// stores SOURCE NODE id per CSR slot
__global__ void k_scatter(const int* __restrict__ dst, const int* __restrict__ src,
                          const int* __restrict__ off,
                          int* __restrict__ cursor, int* __restrict__ slist, int E) {
  int t = blockIdx.x * blockDim.x + threadIdx.x;
  if (t < E) {
    int d = dst[t];
    int p = atomicAdd(&cursor[d], 1);
    slist[off[d] + p] = src[t];
  }
}

// ---------------- converts ----------------
__global__ void k_f2b(const float* __restrict__ x, unsigned short* __restrict__ xb, int n4) {
  int t = blockIdx.x * blockDim.x + threadIdx.x;
  if (t < n4) {
    float4 v = reinterpret_cast<const float4*>(x)[t];
    short4v o;
    o[0] = (short)f2b(v.x); o[1] = (short)f2b(v.y);
    o[2] = (short)f2b(v.z); o[3] = (short)f2b(v.w);
    reinterpret_cast<short4v*>(xb)[t] = o;
  }
}

// W [K,Ncol] f32 -> Wt [Ncol,K] bf16
__global__ __launch_bounds__(256) void k_convT(const float* __restrict__ W,
                                               unsigned short* __restrict__ Wt,
                                               int K, int Ncol) {
  __shared__ float tile[32][33];
  int bx = blockIdx.x * 32;  // Ncol dim
  int by = blockIdx.y * 32;  // K dim
  int tx = threadIdx.x & 31, ty = threadIdx.x >> 5;  // ty 0..7
#pragma unroll
  for (int i = 0; i < 32; i += 8)
    tile[ty + i][tx] = W[(size_t)(by + ty + i) * Ncol + bx + tx];
  __syncthreads();
#pragma unroll
  for (int i = 0; i < 32; i += 8)
    Wt[(size_t)(bx + ty + i) * K + by + tx] = f2b(tile[tx][ty + i]);
}

// assemble concatenated bias vectors in one launch
__global__ void k_bias(const float* __restrict__ b1s, const float* __restrict__ b1d,
                       const float* __restrict__ b1r, const float* __restrict__ b2s,
                       const float* __restrict__ b2d, const float* __restrict__ b2r,
                       float* __restrict__ bias1, float* __restrict__ bias2) {
  int t = blockIdx.x * blockDim.x + threadIdx.x;
  if (t < 1536) {
    bias1[t] = (t < 512) ? b1s[t] : (t < 1024 ? b1d[t - 512] : b1r[t - 1024]);
  } else if (t < 1536 + 3072) {
    int u = t - 1536;
    bias2[u] = (u < 1024) ? b2s[u] : (u < 2048 ? b2d[u - 1024] : b2r[u - 2048]);
  }
}

// ---------------- MFMA GEMM (r8 structure, tile width templated) ----------------
// C[M,Ncol] = A[M,K](bf16) @ Bt[Ncol,K]^T + bias.  Tile: 128 x BN, BK=32.
// 3-buffer rotating pipeline, depth-2 prefetch, raw s_barrier + counted
// vmcnt(stage_ops). XOR col-swizzled LDS; LDS-staged coalesced bf16 epilogue.
template <int BN>
__global__ __launch_bounds__(256) void k_gemm_mfma(const unsigned short* __restrict__ A,
                                                   const unsigned short* __restrict__ Bt,
                                                   const float* __restrict__ bias,
                                                   unsigned short* __restrict__ Cb,
                                                   float* __restrict__ Cf,
                                                   int M, int K, int Ncol, int nbf, int nbn) {
  constexpr int NB = BN / 32;      // n-frags per wave (4 or 8)
  constexpr int BROWS = BN / 64;   // B staging copies per thread (2 or 4)
  constexpr int ABUF = 4096;       // elems per A buffer (128 x 32)
  constexpr int BBUF = BN * 32;    // elems per B buffer
  __shared__ __align__(16) unsigned short lds[3 * (ABUF + BBUF)];  // 24/72 KB; epilogue reuse
  unsigned short* As = lds;
  unsigned short* Bs = lds + 3 * ABUF;

  int nwg = gridDim.x;
  int orig = blockIdx.x;
  int xcd = orig & 7, rest = orig >> 3;
  int q = nwg >> 3, r = nwg & 7;
  int base = (xcd < r) ? xcd * (q + 1) : r * (q + 1) + (xcd - r) * q;
  int wgid = base + rest;
  int bm = (wgid / nbn) * 128, bn = (wgid % nbn) * BN;

  int t = threadIdx.x;
  int l = t & 63, w = t >> 6;
  int wr = w >> 1, wc = w & 1;

  f32x4 acc[4][NB] = {};

  int srow = t >> 2;
  int scol = ((t & 3) * 8) ^ (((srow >> 1) & 3) << 3);  // swizzle invariant under row+=64
  int ga0 = bm + srow;       if (ga0 >= M) ga0 = M - 1;
  int ga1 = bm + srow + 64;  if (ga1 >= M) ga1 = M - 1;
  const unsigned short* pA0 = A + (size_t)ga0 * K + scol;
  const unsigned short* pA1 = A + (size_t)ga1 * K + scol;
  const unsigned short* pB[BROWS];
#pragma unroll
  for (int i = 0; i < BROWS; ++i)
    pB[i] = Bt + (size_t)(bn + srow + 64 * i) * K + scol;  // Ncol multiple of BN

  int aoff[4], boff[NB];
#pragma unroll
  for (int m = 0; m < 4; ++m) {
    int Ra = wr * 64 + m * 16 + (l & 15);
    aoff[m] = Ra * 32 + (((l >> 4) * 8) ^ (((Ra >> 1) & 3) << 3));
  }
#pragma unroll
  for (int n = 0; n < NB; ++n) {
    int Rb = wc * (BN / 2) + n * 16 + (l & 15);
    boff[n] = Rb * 32 + (((l >> 4) * 8) ^ (((Rb >> 1) & 3) << 3));
  }

  auto stage = [&](int buf, int kofs) {
    unsigned short* Ad = As + buf * ABUF;
    unsigned short* Bd = Bs + buf * BBUF;
    async_copy16(pA0 + kofs, Ad + t * 8);
    async_copy16(pA1 + kofs, Ad + 2048 + t * 8);
#pragma unroll
    for (int i = 0; i < BROWS; ++i)
      async_copy16(pB[i] + kofs, Bd + i * 2048 + t * 8);
  };

  auto compute = [&](int buf) {
    const unsigned short* Ab = As + buf * ABUF;
    const unsigned short* Bb = Bs + buf * BBUF;
    short8v af[4], bf[NB];
#pragma unroll
    for (int m = 0; m < 4; ++m) af[m] = *reinterpret_cast<const short8v*>(Ab + aoff[m]);
#pragma unroll
    for (int n = 0; n < NB; ++n) bf[n] = *reinterpret_cast<const short8v*>(Bb + boff[n]);
#pragma unroll
    for (int m = 0; m < 4; ++m)
#pragma unroll
      for (int n = 0; n < NB; ++n)
        acc[m][n] = __builtin_amdgcn_mfma_f32_16x16x32_bf16(af[m], bf[n], acc[m][n], 0, 0, 0);
  };

  int nT = K >> 5;
  stage(0, 0);
  stage(1, 32);
  int rd = 0, wr2 = 2;
  for (int tt = 0; tt < nT - 1; ++tt) {
    // wait: everything except the newest stage batch (tile tt+1) retired
    if constexpr (BN == 128) asm volatile("s_waitcnt vmcnt(4)" ::: "memory");
    else                     asm volatile("s_waitcnt vmcnt(6)" ::: "memory");
    __builtin_amdgcn_s_barrier();
    __builtin_amdgcn_sched_barrier(0);
    if (tt + 2 < nT) stage(wr2, (tt + 2) * 32);
    compute(rd);
    rd = (rd == 2) ? 0 : rd + 1;
    wr2 = (wr2 == 2) ? 0 : wr2 + 1;
  }
  asm volatile("s_waitcnt vmcnt(0)" ::: "memory");
  __builtin_amdgcn_s_barrier();
  __builtin_amdgcn_sched_barrier(0);
  compute(rd);

  bool isbf = (bn < nbf);  // uniform per block
  if (isbf) {
    // ---- LDS-staged coalesced epilogue ----
    __syncthreads();
    constexpr int STR = BN + 8;  // padded row stride (elements); 128*STR fits in lds
#pragma unroll
    for (int m = 0; m < 4; ++m)
#pragma unroll
      for (int qq = 0; qq < 4; ++qq) {
        int rr = wr * 64 + m * 16 + (l >> 4) * 4 + qq;
#pragma unroll
        for (int n = 0; n < NB; ++n) {
          int cc = wc * (BN / 2) + n * 16 + (l & 15);
          lds[rr * STR + cc] = f2b(acc[m][n][qq] + bias[bn + cc]);
        }
      }
    __syncthreads();
    constexpr int CPR = BN / 8;        // 8-elem chunks per row (16 or 32)
    constexpr int RP = 256 / CPR;      // rows per pass (16 or 8)
    int r0 = t / CPR, c0 = (t % CPR) * 8;
#pragma unroll
    for (int it = 0; it < 128 / RP; ++it) {
      int rr = r0 + it * RP;
      int grow = bm + rr;
      if (grow < M) {
        short8v v = *reinterpret_cast<const short8v*>(lds + rr * STR + c0);
        *reinterpret_cast<short8v*>(Cb + (size_t)grow * nbf + bn + c0) = v;
      }
    }
  } else {
#pragma unroll
    for (int m = 0; m < 4; ++m) {
#pragma unroll
      for (int qq = 0; qq < 4; ++qq) {
        int row = bm + wr * 64 + m * 16 + (l >> 4) * 4 + qq;
        if (row < M) {
#pragma unroll
          for (int n = 0; n < NB; ++n) {
            int col = bn + wc * (BN / 2) + n * 16 + (l & 15);
            Cf[(size_t)row * (Ncol - nbf) + (col - nbf)] = acc[m][n][qq] + bias[col];
          }
        }
      }
    }
  }
}

// ---------------- fused edge phase (r12-proven, unchanged) ----------------
template <int D, bool SUMH>
__global__ __launch_bounds__(256) void k_edge_fused(const unsigned short* __restrict__ f1,
                                                    const float* __restrict__ attn,
                                                    const int* __restrict__ off,
                                                    const int* __restrict__ slist,
                                                    const int* __restrict__ order,
                                                    unsigned short* __restrict__ outb,
                                                    int N) {
  constexpr int W = HEADS * D;
  constexpr int W3 = 3 * W;
  constexpr int PER = D / 64;   // elements per lane (4 or 8)
  constexpr int PH = PER / 2;   // f32x2 pairs per lane (2 or 4)
  typedef short rawv __attribute__((ext_vector_type(PER)));
  __shared__ float hs[2][SUMH ? D : 1];

  int w = threadIdx.x >> 6, l = threadIdx.x & 63;
  int slot = blockIdx.x * 2 + (w >> 1);
  int h = w & 1;
  bool active = slot < N;

  f32x2 fdv[PH], av6[PH], av4[PH], acc2[PH];
  float m = -1e30f, s = 0.f;
  int nodeu = 0;

  if (active) {
    nodeu = __builtin_amdgcn_readfirstlane(order[slot]);
    int hD = __builtin_amdgcn_readfirstlane(h * D);
    int b = __builtin_amdgcn_readfirstlane(off[nodeu]);
    int e = __builtin_amdgcn_readfirstlane(off[nodeu + 1]);

    const unsigned short* pfd = f1 + (size_t)nodeu * W3 + W + hD + l * PER;
    const float* pa = attn + hD + l * PER;
#pragma unroll
    for (int j = 0; j < PH; ++j) {
      fdv[j] = bpair(reinterpret_cast<const u32*>(pfd)[j]);
      av6[j].x = 0.6f * pa[2 * j]; av6[j].y = 0.6f * pa[2 * j + 1];
      av4[j].x = 0.4f * pa[2 * j]; av4[j].y = 0.4f * pa[2 * j + 1];
      acc2[j].x = 0.f; acc2[j].y = 0.f;
    }

    auto fetch = [&](rawv* buf, int ii) {
#pragma unroll
      for (int j = 0; j < 4; ++j) {
        int jj = ii + j; jj = (jj < e) ? jj : ii;   // scalar clamp
        int sid = slist[jj];                         // s_load (uniform addr)
        buf[j] = *reinterpret_cast<const rawv*>(
            f1 + (size_t)(u32)sid * W3 + hD + l * PER);
      }
    };

    auto process = [&](const rawv* buf, int i) {
      f32x2 rowf[4][PH];
#pragma unroll
      for (int j = 0; j < 4; ++j) {
        const u32* ru = reinterpret_cast<const u32*>(&buf[j]);
#pragma unroll
        for (int k = 0; k < PH; ++k) rowf[j][k] = bpair(ru[k]);
      }
      float part[4];
#pragma unroll
      for (int j = 0; j < 4; ++j) {
        f32x2 lacc = {0.f, 0.f};
#pragma unroll
        for (int k = 0; k < PH; ++k) {
          f32x2 sv = pk_add(rowf[j][k], fdv[k]);
          f32x2 ab = pk_abs(sv);
          lacc = pk_fma(sv, av6[k], lacc);
          lacc = pk_fma(ab, av4[k], lacc);
        }
        part[j] = lacc.x + lacc.y;
      }
#pragma unroll
      for (int o = 1; o < 64; o <<= 1) {
#pragma unroll
        for (int j = 0; j < 4; ++j) part[j] += __shfl_xor(part[j], o, 64);
      }
#pragma unroll
      for (int j = 0; j < 4; ++j) {
        if (i + j < e) {
          float pj = part[j];
          if (pj <= m) {
            float p = __expf(pj - m);
            s += p;
            f32x2 pp = {p, p};
#pragma unroll
            for (int k = 0; k < PH; ++k) acc2[k] = pk_fma(rowf[j][k], pp, acc2[k]);
          } else {
            float c = (m == -1e30f) ? 0.f : __expf(m - pj);
            s = s * c + 1.f;
            f32x2 cc = {c, c};
#pragma unroll
            for (int k = 0; k < PH; ++k) acc2[k] = pk_fma(acc2[k], cc, rowf[j][k]);
            m = pj;
          }
        }
      }
    };

    if (b < e) {
      rawv A[4], B[4];
      fetch(A, b);
      int i = b;
      while (true) {
        if (i + 4 < e) fetch(B, i + 4);
        process(A, i);
        i += 4;
        if (i >= e) break;
        if (i + 4 < e) fetch(A, i + 4);
        process(B, i);
        i += 4;
        if (i >= e) break;
      }
    }

    float inv = (s > 0.f) ? 1.f / s : 0.f;
    const unsigned short* pr = f1 + (size_t)nodeu * W3 + 2 * W + hD + l * PER;
    f32x2 iv = {inv, inv};
#pragma unroll
    for (int j = 0; j < PH; ++j) {
      f32x2 rr = bpair(reinterpret_cast<const u32*>(pr)[j]);
      f32x2 v = pk_fma(acc2[j], iv, rr);
      v.x = v.x > 0.f ? v.x : 0.f;
      v.y = v.y > 0.f ? v.y : 0.f;
      acc2[j] = v;  // relu'd
    }
  }

  if constexpr (SUMH) {
    if (active && h == 0) {
#pragma unroll
      for (int j = 0; j < PH; ++j) {
        hs[w >> 1][l * PER + 2 * j] = acc2[j].x;
        hs[w >> 1][l * PER + 2 * j + 1] = acc2[j].y;
      }
    }
    __syncthreads();
    if (active && h == 1) {
      short8v o;
#pragma unroll
      for (int j = 0; j < PH; ++j) {
        o[2 * j] = (short)f2b(acc2[j].x + hs[w >> 1][l * PER + 2 * j]);
        o[2 * j + 1] = (short)f2b(acc2[j].y + hs[w >> 1][l * PER + 2 * j + 1]);
      }
      *reinterpret_cast<short8v*>(outb + (size_t)nodeu * D + l * PER) = o;
    }
  } else {
    if (active) {
      short4v o;
#pragma unroll
      for (int j = 0; j < PH; ++j) {
        o[2 * j] = (short)f2b(acc2[j].x);
        o[2 * j + 1] = (short)f2b(acc2[j].y);
      }
      *reinterpret_cast<short4v*>(outb + (size_t)nodeu * W + h * D + l * PER) = o;
    }
  }
}

extern "C" void kernel_launch(void* const* d_in, const int* in_sizes, int n_in,
                              void* d_out, int out_size, void* d_ws, size_t ws_size,
                              hipStream_t stream) {
  const float* x    = (const float*)d_in[0];
  const int*   src  = (const int*)d_in[1];
  const int*   dst  = (const int*)d_in[2];
  const float* W1s  = (const float*)d_in[3];
  const float* b1s  = (const float*)d_in[4];
  const float* W1d  = (const float*)d_in[5];
  const float* b1d  = (const float*)d_in[6];
  const float* at1  = (const float*)d_in[7];
  const float* W1r  = (const float*)d_in[8];
  const float* b1r  = (const float*)d_in[9];
  const float* W2s  = (const float*)d_in[10];
  const float* b2s  = (const float*)d_in[11];
  const float* W2d  = (const float*)d_in[12];
  const float* b2d  = (const float*)d_in[13];
  const float* at2  = (const float*)d_in[14];
  const float* W2r  = (const float*)d_in[15];
  const float* b2r  = (const float*)d_in[16];
  const float* Wp   = (const float*)d_in[17];
  const float* bp   = (const float*)d_in[18];
  float* out = (float*)d_out;

  const int N = in_sizes[0] / 1024;  // 10000
  const int E = in_sizes[1];         // 160000

  // ---- workspace layout ----
  char* ws = (char*)d_ws;
  size_t o = 0;
  auto alloc = [&](size_t bytes) { char* p = ws + o; o += (bytes + 255) & ~(size_t)255; return p; };
  unsigned short* xb    = (unsigned short*)alloc((size_t)N * 1024 * 2);
  unsigned short* w1cat = (unsigned short*)alloc((size_t)1536 * 1024 * 2);
  unsigned short* w2cat = (unsigned short*)alloc((size_t)3072 * 512 * 2);
  unsigned short* wp    = (unsigned short*)alloc((size_t)512 * 512 * 2);
  float*          bias1 = (float*)alloc(1536 * 4);
  float*          bias2 = (float*)alloc(3072 * 4);
  unsigned short* f1    = (unsigned short*)alloc((size_t)N * 3072 * 2);  // fs||fd||res
  unsigned short* h1    = (unsigned short*)alloc((size_t)N * 512 * 2);
  unsigned short* h2    = (unsigned short*)alloc((size_t)N * 512 * 2);
  // zero-span: deg | cursor | dcur | hist (one memset)
  int* deg    = (int*)alloc((size_t)N * 4);
  int* cursor = (int*)alloc((size_t)N * 4);
  int* dcur   = (int*)alloc(256 * 4);
  int* hist   = (int*)alloc(256 * 4);
  int* dbase  = (int*)alloc(256 * 4);
  int* offp   = (int*)alloc((size_t)(N + 1) * 4);
  int* order  = (int*)alloc((size_t)N * 4);
  int* slist  = (int*)alloc((size_t)E * 4);
  if (o > ws_size) return;

  // ---- CSR build + degree sort ----
  size_t zlen = (size_t)((char*)(hist + 256) - (char*)deg);
  hipMemsetAsync(deg, 0, zlen, stream);
  k_count<<<(E + 255) / 256, 256, 0, stream>>>(dst, deg, E);
  k_hist<<<40, 256, 0, stream>>>(deg, hist, N);
  k_scan<<<1, 1024, 0, stream>>>(deg, offp, hist, dbase, N);
  k_place<<<(N + 255) / 256, 256, 0, stream>>>(deg, dbase, dcur, order, N);
  k_scatter<<<(E + 255) / 256, 256, 0, stream>>>(dst, src, offp, cursor, slist, E);

  // ---- converts ----
  k_f2b<<<((N * 1024 / 4) + 255) / 256, 256, 0, stream>>>(x, xb, N * 1024 / 4);
  {
    dim3 gT1(512 / 32, 1024 / 32);
    k_convT<<<gT1, 256, 0, stream>>>(W1s, w1cat + (size_t)0 * 1024, 1024, 512);
    k_convT<<<gT1, 256, 0, stream>>>(W1d, w1cat + (size_t)512 * 1024, 1024, 512);
    k_convT<<<gT1, 256, 0, stream>>>(W1r, w1cat + (size_t)1024 * 1024, 1024, 512);
    dim3 gT2(1024 / 32, 512 / 32);
    k_convT<<<gT2, 256, 0, stream>>>(W2s, w2cat + (size_t)0 * 512, 512, 1024);
    k_convT<<<gT2, 256, 0, stream>>>(W2d, w2cat + (size_t)1024 * 512, 512, 1024);
    k_convT<<<gT2, 256, 0, stream>>>(W2r, w2cat + (size_t)2048 * 512, 512, 1024);
    dim3 gT3(512 / 32, 512 / 32);
    k_convT<<<gT3, 256, 0, stream>>>(Wp, wp, 512, 512);
  }
  k_bias<<<(1536 + 3072 + 255) / 256, 256, 0, stream>>>(b1s, b1d, b1r, b2s, b2d, b2r,
                                                        bias1, bias2);

  int nbm = (N + 127) / 128;  // 79

  // ---- conv1: [N,1024] @ [1024,1536] -> f1[N,1536] bf16 (fs|fd|res) ----
  k_gemm_mfma<256><<<nbm * (1536 / 256), 256, 0, stream>>>(xb, w1cat, bias1, f1, nullptr,
                                                           N, 1024, 1536, 1536, 1536 / 256);
  k_edge_fused<256, false><<<(N + 1) / 2, 256, 0, stream>>>(f1, at1, offp, slist, order, h1, N);

  // ---- conv2: [N,512] @ [512,3072] -> f1[N,3072] bf16 (fs|fd|res) ----
  k_gemm_mfma<256><<<nbm * (3072 / 256), 256, 0, stream>>>(h1, w2cat, bias2, f1, nullptr,
                                                           N, 512, 3072, 3072, 3072 / 256);
  k_edge_fused<512, true><<<(N + 1) / 2, 256, 0, stream>>>(f1, at2, offp, slist, order, h2, N);

  // ---- projection: h2[N,512] @ [512,512] -> out f32 (final relu no-op) ----
  k_gemm_mfma<128><<<nbm * (512 / 128), 256, 0, stream>>>(h2, wp, bp, nullptr, out,
                                                          N, 512, 512, 0, 512 / 128);
}

// Round 14
// 261.153 us; speedup vs baseline: 1.1513x; 1.1513x over previous
//
#include <hip/hip_runtime.h>
#include <math.h>

static constexpr int HEADS = 2;

typedef unsigned int u32;
typedef __attribute__((ext_vector_type(4))) short short4v;
typedef __attribute__((ext_vector_type(8))) short short8v;
typedef __attribute__((ext_vector_type(4))) float f32x4;
typedef __attribute__((ext_vector_type(2))) float f32x2;

__device__ __forceinline__ unsigned short f2b(float f) {
  union { float f; u32 u; } v; v.f = f;
  u32 u = v.u;
  u32 r = (u + 0x7fffu + ((u >> 16) & 1u)) >> 16;  // RNE
  return (unsigned short)r;
}
__device__ __forceinline__ float b2f(unsigned short b) {
  union { u32 u; float f; } v; v.u = ((u32)b) << 16;
  return v.f;
}
// unpack u32 holding 2 bf16 -> f32x2 {lo, hi}
__device__ __forceinline__ f32x2 bpair(u32 u) {
  union { u32 u; float f; } a, b;
  a.u = u << 16; b.u = u & 0xffff0000u;
  f32x2 r; r.x = a.f; r.y = b.f; return r;
}

// packed fp32 VOP3P ops (gfx90a+)
__device__ __forceinline__ f32x2 pk_add(f32x2 a, f32x2 b) {
  f32x2 d; asm("v_pk_add_f32 %0, %1, %2" : "=v"(d) : "v"(a), "v"(b)); return d;
}
__device__ __forceinline__ f32x2 pk_fma(f32x2 a, f32x2 b, f32x2 c) {
  f32x2 d; asm("v_pk_fma_f32 %0, %1, %2, %3" : "=v"(d) : "v"(a), "v"(b), "v"(c)); return d;
}
__device__ __forceinline__ f32x2 pk_abs(f32x2 a) {
  union { f32x2 f; u32 u[2]; } v; v.f = a;
  v.u[0] &= 0x7fffffffu; v.u[1] &= 0x7fffffffu; return v.f;
}

__device__ __forceinline__ void async_copy16(const void* g, void* l) {
  __builtin_amdgcn_global_load_lds(
      (const __attribute__((address_space(1))) u32*)g,
      (__attribute__((address_space(3))) u32*)l, 16, 0, 0);
}

// ---------------- CSR build ----------------
__global__ void k_count(const int* __restrict__ dst, int* __restrict__ deg, int E) {
  int t = blockIdx.x * blockDim.x + threadIdx.x;
  if (t < E) atomicAdd(&deg[dst[t]], 1);
}

__global__ void k_scan(const int* __restrict__ deg, int* __restrict__ off, int n) {
  __shared__ int part[1024];
  int t = threadIdx.x;
  int per = (n + 1023) >> 10;
  int s0 = t * per, s1 = min(s0 + per, n);
  int s = 0;
  for (int i = s0; i < s1; ++i) s += deg[i];
  part[t] = s;
  __syncthreads();
  for (int d = 1; d < 1024; d <<= 1) {
    int v = (t >= d) ? part[t - d] : 0;
    __syncthreads();
    part[t] += v;
    __syncthreads();
  }
  int base = (t == 0) ? 0 : part[t - 1];
  for (int i = s0; i < s1; ++i) { off[i] = base; base += deg[i]; }
  if (t == 1023) off[n] = part[1023];
}

// stores SOURCE NODE id per CSR slot
__global__ void k_scatter(const int* __restrict__ dst, const int* __restrict__ src,
                          const int* __restrict__ off,
                          int* __restrict__ cursor, int* __restrict__ slist, int E) {
  int t = blockIdx.x * blockDim.x + threadIdx.x;
  if (t < E) {
    int d = dst[t];
    int p = atomicAdd(&cursor[d], 1);
    slist[off[d] + p] = src[t];
  }
}

// ---------------- converts ----------------
__global__ void k_f2b(const float* __restrict__ x, unsigned short* __restrict__ xb, int n4) {
  int t = blockIdx.x * blockDim.x + threadIdx.x;
  if (t < n4) {
    float4 v = reinterpret_cast<const float4*>(x)[t];
    short4v o;
    o[0] = (short)f2b(v.x); o[1] = (short)f2b(v.y);
    o[2] = (short)f2b(v.z); o[3] = (short)f2b(v.w);
    reinterpret_cast<short4v*>(xb)[t] = o;
  }
}

// W [K,Ncol] f32 -> Wt [Ncol,K] bf16
__global__ __launch_bounds__(256) void k_convT(const float* __restrict__ W,
                                               unsigned short* __restrict__ Wt,
                                               int K, int Ncol) {
  __shared__ float tile[32][33];
  int bx = blockIdx.x * 32;  // Ncol dim
  int by = blockIdx.y * 32;  // K dim
  int tx = threadIdx.x & 31, ty = threadIdx.x >> 5;  // ty 0..7
#pragma unroll
  for (int i = 0; i < 32; i += 8)
    tile[ty + i][tx] = W[(size_t)(by + ty + i) * Ncol + bx + tx];
  __syncthreads();
#pragma unroll
  for (int i = 0; i < 32; i += 8)
    Wt[(size_t)(bx + ty + i) * K + by + tx] = f2b(tile[tx][ty + i]);
}

// assemble concatenated bias vectors in one launch
__global__ void k_bias(const float* __restrict__ b1s, const float* __restrict__ b1d,
                       const float* __restrict__ b1r, const float* __restrict__ b2s,
                       const float* __restrict__ b2d, const float* __restrict__ b2r,
                       float* __restrict__ bias1, float* __restrict__ bias2) {
  int t = blockIdx.x * blockDim.x + threadIdx.x;
  if (t < 1536) {
    bias1[t] = (t < 512) ? b1s[t] : (t < 1024 ? b1d[t - 512] : b1r[t - 1024]);
  } else if (t < 1536 + 3072) {
    int u = t - 1536;
    bias2[u] = (u < 1024) ? b2s[u] : (u < 2048 ? b2d[u - 1024] : b2r[u - 2048]);
  }
}

// ---------------- MFMA GEMM (round-8 proven, unchanged) ----------------
__global__ __launch_bounds__(256) void k_gemm_mfma(const unsigned short* __restrict__ A,
                                                   const unsigned short* __restrict__ Bt,
                                                   const float* __restrict__ bias,
                                                   unsigned short* __restrict__ Cb,
                                                   float* __restrict__ Cf,
                                                   int M, int K, int Ncol, int nbf, int nbn) {
  __shared__ __align__(16) unsigned short lds[24576];  // 48 KB; reused by epilogue
  unsigned short* As = lds;
  unsigned short* Bs = lds + 12288;

  int nwg = gridDim.x;
  int orig = blockIdx.x;
  int xcd = orig & 7, rest = orig >> 3;
  int q = nwg >> 3, r = nwg & 7;
  int base = (xcd < r) ? xcd * (q + 1) : r * (q + 1) + (xcd - r) * q;
  int wgid = base + rest;
  int bm = (wgid / nbn) * 128, bn = (wgid % nbn) * 128;

  int t = threadIdx.x;
  int l = t & 63, w = t >> 6;
  int wr = w >> 1, wc = w & 1;

  f32x4 acc[4][4] = {};

  int srow = t >> 2;
  int scol = ((t & 3) * 8) ^ (((srow >> 1) & 3) << 3);
  int ga0 = bm + srow;       if (ga0 >= M) ga0 = M - 1;
  int ga1 = bm + srow + 64;  if (ga1 >= M) ga1 = M - 1;
  const unsigned short* pA0 = A + (size_t)ga0 * K + scol;
  const unsigned short* pA1 = A + (size_t)ga1 * K + scol;
  const unsigned short* pB0 = Bt + (size_t)(bn + srow) * K + scol;
  const unsigned short* pB1 = Bt + (size_t)(bn + srow + 64) * K + scol;

  int aoff[4], boff[4];
#pragma unroll
  for (int m = 0; m < 4; ++m) {
    int Ra = wr * 64 + m * 16 + (l & 15);
    aoff[m] = Ra * 32 + (((l >> 4) * 8) ^ (((Ra >> 1) & 3) << 3));
    int Rb = wc * 64 + m * 16 + (l & 15);
    boff[m] = Rb * 32 + (((l >> 4) * 8) ^ (((Rb >> 1) & 3) << 3));
  }

  auto stage = [&](int buf, int kofs) {
    unsigned short* Ad = As + buf * 4096;
    unsigned short* Bd = Bs + buf * 4096;
    async_copy16(pA0 + kofs, Ad + t * 8);
    async_copy16(pA1 + kofs, Ad + 2048 + t * 8);
    async_copy16(pB0 + kofs, Bd + t * 8);
    async_copy16(pB1 + kofs, Bd + 2048 + t * 8);
  };

  auto compute = [&](int buf) {
    const unsigned short* Ab = As + buf * 4096;
    const unsigned short* Bb = Bs + buf * 4096;
    short8v af[4], bf[4];
#pragma unroll
    for (int m = 0; m < 4; ++m) af[m] = *reinterpret_cast<const short8v*>(Ab + aoff[m]);
#pragma unroll
    for (int n = 0; n < 4; ++n) bf[n] = *reinterpret_cast<const short8v*>(Bb + boff[n]);
#pragma unroll
    for (int m = 0; m < 4; ++m)
#pragma unroll
      for (int n = 0; n < 4; ++n)
        acc[m][n] = __builtin_amdgcn_mfma_f32_16x16x32_bf16(af[m], bf[n], acc[m][n], 0, 0, 0);
  };

  int nT = K >> 5;
  stage(0, 0);
  stage(1, 32);
  int rd = 0, wr2 = 2;
  for (int tt = 0; tt < nT - 1; ++tt) {
    asm volatile("s_waitcnt vmcnt(4)" ::: "memory");
    __builtin_amdgcn_s_barrier();
    __builtin_amdgcn_sched_barrier(0);
    if (tt + 2 < nT) stage(wr2, (tt + 2) * 32);
    compute(rd);
    rd = (rd == 2) ? 0 : rd + 1;
    wr2 = (wr2 == 2) ? 0 : wr2 + 1;
  }
  asm volatile("s_waitcnt vmcnt(0)" ::: "memory");
  __builtin_amdgcn_s_barrier();
  __builtin_amdgcn_sched_barrier(0);
  compute(rd);

  bool isbf = (bn < nbf);
  if (isbf) {
    __syncthreads();
#pragma unroll
    for (int m = 0; m < 4; ++m)
#pragma unroll
      for (int qq = 0; qq < 4; ++qq) {
        int rr = wr * 64 + m * 16 + (l >> 4) * 4 + qq;
#pragma unroll
        for (int n = 0; n < 4; ++n) {
          int cc = wc * 64 + n * 16 + (l & 15);
          lds[rr * 136 + cc] = f2b(acc[m][n][qq] + bias[bn + cc]);
        }
      }
    __syncthreads();
    int r0 = t >> 4, c0 = (t & 15) * 8;
#pragma unroll
    for (int it = 0; it < 8; ++it) {
      int rr = r0 + it * 16;
      int grow = bm + rr;
      if (grow < M) {
        short8v v = *reinterpret_cast<const short8v*>(lds + rr * 136 + c0);
        *reinterpret_cast<short8v*>(Cb + (size_t)grow * nbf + bn + c0) = v;
      }
    }
  } else {
#pragma unroll
    for (int m = 0; m < 4; ++m) {
#pragma unroll
      for (int qq = 0; qq < 4; ++qq) {
        int row = bm + wr * 64 + m * 16 + (l >> 4) * 4 + qq;
        if (row < M) {
#pragma unroll
          for (int n = 0; n < 4; ++n) {
            int col = bn + wc * 64 + n * 16 + (l & 15);
            Cf[(size_t)row * (Ncol - nbf) + (col - nbf)] = acc[m][n][qq] + bias[col];
          }
        }
      }
    }
  }
}

// ---------------- fused edge phase ----------------
// f1[N, 3W] bf16: cols [0,W)=fs, [W,2W)=fd, [2W,3W)=res.  attn[H,D] f32.
// One wave per (node, head). Scalar CSR walk (s_load indices).
// THREE-group software pipeline: 12 gathered rows in flight per wave.
template <int D, bool SUMH>
__global__ __launch_bounds__(256) void k_edge_fused(const unsigned short* __restrict__ f1,
                                                    const float* __restrict__ attn,
                                                    const int* __restrict__ off,
                                                    const int* __restrict__ slist,
                                                    unsigned short* __restrict__ outb,
                                                    int N) {
  constexpr int W = HEADS * D;
  constexpr int W3 = 3 * W;
  constexpr int PER = D / 64;   // elements per lane (4 or 8)
  constexpr int PH = PER / 2;   // f32x2 pairs per lane (2 or 4)
  typedef short rawv __attribute__((ext_vector_type(PER)));
  __shared__ float hs[2][SUMH ? D : 1];

  int w = threadIdx.x >> 6, l = threadIdx.x & 63;
  int node = blockIdx.x * 2 + (w >> 1);
  int h = w & 1;
  bool active = node < N;

  f32x2 fdv[PH], av6[PH], av4[PH], acc2[PH];
  float m = -1e30f, s = 0.f;

  if (active) {
    // wave-uniform scalars, made provable for the compiler
    int hD = __builtin_amdgcn_readfirstlane(h * D);
    int nodeu = __builtin_amdgcn_readfirstlane(node);
    int b = __builtin_amdgcn_readfirstlane(off[nodeu]);
    int e = __builtin_amdgcn_readfirstlane(off[nodeu + 1]);

    const unsigned short* pfd = f1 + (size_t)nodeu * W3 + W + hD + l * PER;
    const float* pa = attn + hD + l * PER;
#pragma unroll
    for (int j = 0; j < PH; ++j) {
      fdv[j] = bpair(reinterpret_cast<const u32*>(pfd)[j]);
      av6[j].x = 0.6f * pa[2 * j]; av6[j].y = 0.6f * pa[2 * j + 1];
      av4[j].x = 0.4f * pa[2 * j]; av4[j].y = 0.4f * pa[2 * j + 1];
      acc2[j].x = 0.f; acc2[j].y = 0.f;
    }

    // fetch group of 4 rows at CSR positions [ii, ii+4) (clamped) into buf
    auto fetch = [&](rawv* buf, int ii) {
#pragma unroll
      for (int j = 0; j < 4; ++j) {
        int jj = ii + j; jj = (jj < e) ? jj : ii;   // scalar clamp
        int sid = slist[jj];                         // s_load (uniform addr)
        buf[j] = *reinterpret_cast<const rawv*>(
            f1 + (size_t)(u32)sid * W3 + hD + l * PER);
      }
    };

    // process group of 4 rows starting at CSR position i
    auto process = [&](const rawv* buf, int i) {
      f32x2 rowf[4][PH];
#pragma unroll
      for (int j = 0; j < 4; ++j) {
        const u32* ru = reinterpret_cast<const u32*>(&buf[j]);
#pragma unroll
        for (int k = 0; k < PH; ++k) rowf[j][k] = bpair(ru[k]);
      }
      float part[4];
#pragma unroll
      for (int j = 0; j < 4; ++j) {
        f32x2 lacc = {0.f, 0.f};
#pragma unroll
        for (int k = 0; k < PH; ++k) {
          f32x2 sv = pk_add(rowf[j][k], fdv[k]);
          f32x2 ab = pk_abs(sv);
          lacc = pk_fma(sv, av6[k], lacc);
          lacc = pk_fma(ab, av4[k], lacc);
        }
        part[j] = lacc.x + lacc.y;
      }
#pragma unroll
      for (int o = 1; o < 64; o <<= 1) {
#pragma unroll
        for (int j = 0; j < 4; ++j) part[j] += __shfl_xor(part[j], o, 64);
      }
#pragma unroll
      for (int j = 0; j < 4; ++j) {
        if (i + j < e) {
          float pj = part[j];
          if (pj <= m) {
            float p = __expf(pj - m);
            s += p;
            f32x2 pp = {p, p};
#pragma unroll
            for (int k = 0; k < PH; ++k) acc2[k] = pk_fma(rowf[j][k], pp, acc2[k]);
          } else {
            float c = (m == -1e30f) ? 0.f : __expf(m - pj);
            s = s * c + 1.f;
            f32x2 cc = {c, c};
#pragma unroll
            for (int k = 0; k < PH; ++k) acc2[k] = pk_fma(acc2[k], cc, rowf[j][k]);
            m = pj;
          }
        }
      }
    };

    if (b < e) {
      rawv A[4], B[4], C[4];
      fetch(A, b);
      if (b + 4 < e) fetch(B, b + 4);
      int i = b;
      while (true) {
        if (i + 8 < e) fetch(C, i + 8);
        process(A, i);
        i += 4;
        if (i >= e) break;
        if (i + 8 < e) fetch(A, i + 8);
        process(B, i);
        i += 4;
        if (i >= e) break;
        if (i + 8 < e) fetch(B, i + 8);
        process(C, i);
        i += 4;
        if (i >= e) break;
      }
    }

    float inv = (s > 0.f) ? 1.f / s : 0.f;
    const unsigned short* pr = f1 + (size_t)nodeu * W3 + 2 * W + hD + l * PER;
    f32x2 iv = {inv, inv};
#pragma unroll
    for (int j = 0; j < PH; ++j) {
      f32x2 rr = bpair(reinterpret_cast<const u32*>(pr)[j]);
      f32x2 v = pk_fma(acc2[j], iv, rr);
      v.x = v.x > 0.f ? v.x : 0.f;
      v.y = v.y > 0.f ? v.y : 0.f;
      acc2[j] = v;  // relu'd
    }
  }

  if constexpr (SUMH) {
    if (active && h == 0) {
#pragma unroll
      for (int j = 0; j < PH; ++j) {
        hs[w >> 1][l * PER + 2 * j] = acc2[j].x;
        hs[w >> 1][l * PER + 2 * j + 1] = acc2[j].y;
      }
    }
    __syncthreads();
    if (active && h == 1) {
      short8v o;
#pragma unroll
      for (int j = 0; j < PH; ++j) {
        o[2 * j] = (short)f2b(acc2[j].x + hs[w >> 1][l * PER + 2 * j]);
        o[2 * j + 1] = (short)f2b(acc2[j].y + hs[w >> 1][l * PER + 2 * j + 1]);
      }
      *reinterpret_cast<short8v*>(outb + (size_t)node * D + l * PER) = o;
    }
  } else {
    if (active) {
      short4v o;
#pragma unroll
      for (int j = 0; j < PH; ++j) {
        o[2 * j] = (short)f2b(acc2[j].x);
        o[2 * j + 1] = (short)f2b(acc2[j].y);
      }
      *reinterpret_cast<short4v*>(outb + (size_t)node * W + h * D + l * PER) = o;
    }
  }
}

extern "C" void kernel_launch(void* const* d_in, const int* in_sizes, int n_in,
                              void* d_out, int out_size, void* d_ws, size_t ws_size,
                              hipStream_t stream) {
  const float* x    = (const float*)d_in[0];
  const int*   src  = (const int*)d_in[1];
  const int*   dst  = (const int*)d_in[2];
  const float* W1s  = (const float*)d_in[3];
  const float* b1s  = (const float*)d_in[4];
  const float* W1d  = (const float*)d_in[5];
  const float* b1d  = (const float*)d_in[6];
  const float* at1  = (const float*)d_in[7];
  const float* W1r  = (const float*)d_in[8];
  const float* b1r  = (const float*)d_in[9];
  const float* W2s  = (const float*)d_in[10];
  const float* b2s  = (const float*)d_in[11];
  const float* W2d  = (const float*)d_in[12];
  const float* b2d  = (const float*)d_in[13];
  const float* at2  = (const float*)d_in[14];
  const float* W2r  = (const float*)d_in[15];
  const float* b2r  = (const float*)d_in[16];
  const float* Wp   = (const float*)d_in[17];
  const float* bp   = (const float*)d_in[18];
  float* out = (float*)d_out;

  const int N = in_sizes[0] / 1024;  // 10000
  const int E = in_sizes[1];         // 160000

  // ---- workspace layout ----
  char* ws = (char*)d_ws;
  size_t o = 0;
  auto alloc = [&](size_t bytes) { char* p = ws + o; o += (bytes + 255) & ~(size_t)255; return p; };
  unsigned short* xb    = (unsigned short*)alloc((size_t)N * 1024 * 2);
  unsigned short* w1cat = (unsigned short*)alloc((size_t)1536 * 1024 * 2);
  unsigned short* w2cat = (unsigned short*)alloc((size_t)3072 * 512 * 2);
  unsigned short* wp    = (unsigned short*)alloc((size_t)512 * 512 * 2);
  float*          bias1 = (float*)alloc(1536 * 4);
  float*          bias2 = (float*)alloc(3072 * 4);
  unsigned short* f1    = (unsigned short*)alloc((size_t)N * 3072 * 2);  // fs||fd||res
  unsigned short* h1    = (unsigned short*)alloc((size_t)N * 512 * 2);
  unsigned short* h2    = (unsigned short*)alloc((size_t)N * 512 * 2);
  int* deg    = (int*)alloc((size_t)N * 4);
  int* cursor = (int*)alloc((size_t)N * 4);
  int* offp   = (int*)alloc((size_t)(N + 1) * 4);
  int* slist  = (int*)alloc((size_t)E * 4);
  if (o > ws_size) return;

  // ---- CSR build ----
  size_t zlen = (size_t)((char*)(cursor + N) - (char*)deg);
  hipMemsetAsync(deg, 0, zlen, stream);
  k_count<<<(E + 255) / 256, 256, 0, stream>>>(dst, deg, E);
  k_scan<<<1, 1024, 0, stream>>>(deg, offp, N);
  k_scatter<<<(E + 255) / 256, 256, 0, stream>>>(dst, src, offp, cursor, slist, E);

  // ---- converts ----
  k_f2b<<<((N * 1024 / 4) + 255) / 256, 256, 0, stream>>>(x, xb, N * 1024 / 4);
  {
    dim3 gT1(512 / 32, 1024 / 32);
    k_convT<<<gT1, 256, 0, stream>>>(W1s, w1cat + (size_t)0 * 1024, 1024, 512);
    k_convT<<<gT1, 256, 0, stream>>>(W1d, w1cat + (size_t)512 * 1024, 1024, 512);
    k_convT<<<gT1, 256, 0, stream>>>(W1r, w1cat + (size_t)1024 * 1024, 1024, 512);
    dim3 gT2(1024 / 32, 512 / 32);
    k_convT<<<gT2, 256, 0, stream>>>(W2s, w2cat + (size_t)0 * 512, 512, 1024);
    k_convT<<<gT2, 256, 0, stream>>>(W2d, w2cat + (size_t)1024 * 512, 512, 1024);
    k_convT<<<gT2, 256, 0, stream>>>(W2r, w2cat + (size_t)2048 * 512, 512, 1024);
    dim3 gT3(512 / 32, 512 / 32);
    k_convT<<<gT3, 256, 0, stream>>>(Wp, wp, 512, 512);
  }
  k_bias<<<(1536 + 3072 + 255) / 256, 256, 0, stream>>>(b1s, b1d, b1r, b2s, b2d, b2r,
                                                        bias1, bias2);

  int nbm = (N + 127) / 128;  // 79

  // ---- conv1: [N,1024] @ [1024,1536] -> f1[N,1536] bf16 (fs|fd|res) ----
  k_gemm_mfma<<<nbm * (1536 / 128), 256, 0, stream>>>(xb, w1cat, bias1, f1, nullptr,
                                                      N, 1024, 1536, 1536, 1536 / 128);
  k_edge_fused<256, false><<<(N + 1) / 2, 256, 0, stream>>>(f1, at1, offp, slist, h1, N);

  // ---- conv2: [N,512] @ [512,3072] -> f1[N,3072] bf16 (fs|fd|res) ----
  k_gemm_mfma<<<nbm * (3072 / 128), 256, 0, stream>>>(h1, w2cat, bias2, f1, nullptr,
                                                      N, 512, 3072, 3072, 3072 / 128);
  k_edge_fused<512, true><<<(N + 1) / 2, 256, 0, stream>>>(f1, at2, offp, slist, h2, N);

  // ---- projection: h2[N,512] @ [512,512] -> out f32 (final relu no-op) ----
  k_gemm_mfma<<<nbm * (512 / 128), 256, 0, stream>>>(h2, wp, bp, nullptr, out,
                                                     N, 512, 512, 0, 512 / 128);
}

// Round 15
// 256.470 us; speedup vs baseline: 1.1723x; 1.0183x over previous
//
#include <hip/hip_runtime.h>
#include <math.h>

static constexpr int HEADS = 2;

typedef unsigned int u32;
typedef __attribute__((ext_vector_type(4))) short short4v;
typedef __attribute__((ext_vector_type(8))) short short8v;
typedef __attribute__((ext_vector_type(4))) float f32x4;
typedef __attribute__((ext_vector_type(2))) float f32x2;

__device__ __forceinline__ unsigned short f2b(float f) {
  union { float f; u32 u; } v; v.f = f;
  u32 u = v.u;
  u32 r = (u + 0x7fffu + ((u >> 16) & 1u)) >> 16;  // RNE
  return (unsigned short)r;
}
__device__ __forceinline__ float b2f(unsigned short b) {
  union { u32 u; float f; } v; v.u = ((u32)b) << 16;
  return v.f;
}
// unpack u32 holding 2 bf16 -> f32x2 {lo, hi}
__device__ __forceinline__ f32x2 bpair(u32 u) {
  union { u32 u; float f; } a, b;
  a.u = u << 16; b.u = u & 0xffff0000u;
  f32x2 r; r.x = a.f; r.y = b.f; return r;
}

// packed fp32 VOP3P ops (gfx90a+)
__device__ __forceinline__ f32x2 pk_add(f32x2 a, f32x2 b) {
  f32x2 d; asm("v_pk_add_f32 %0, %1, %2" : "=v"(d) : "v"(a), "v"(b)); return d;
}
__device__ __forceinline__ f32x2 pk_fma(f32x2 a, f32x2 b, f32x2 c) {
  f32x2 d; asm("v_pk_fma_f32 %0, %1, %2, %3" : "=v"(d) : "v"(a), "v"(b), "v"(c)); return d;
}
__device__ __forceinline__ f32x2 pk_abs(f32x2 a) {
  union { f32x2 f; u32 u[2]; } v; v.f = a;
  v.u[0] &= 0x7fffffffu; v.u[1] &= 0x7fffffffu; return v.f;
}

__device__ __forceinline__ void async_copy16(const void* g, void* l) {
  __builtin_amdgcn_global_load_lds(
      (const __attribute__((address_space(1))) u32*)g,
      (__attribute__((address_space(3))) u32*)l, 16, 0, 0);
}

// ---------------- CSR build ----------------
__global__ void k_count(const int* __restrict__ dst, int* __restrict__ deg, int E) {
  int t = blockIdx.x * blockDim.x + threadIdx.x;
  if (t < E) atomicAdd(&deg[dst[t]], 1);
}

__global__ void k_scan(const int* __restrict__ deg, int* __restrict__ off, int n) {
  __shared__ int part[1024];
  int t = threadIdx.x;
  int per = (n + 1023) >> 10;
  int s0 = t * per, s1 = min(s0 + per, n);
  int s = 0;
  for (int i = s0; i < s1; ++i) s += deg[i];
  part[t] = s;
  __syncthreads();
  for (int d = 1; d < 1024; d <<= 1) {
    int v = (t >= d) ? part[t - d] : 0;
    __syncthreads();
    part[t] += v;
    __syncthreads();
  }
  int base = (t == 0) ? 0 : part[t - 1];
  for (int i = s0; i < s1; ++i) { off[i] = base; base += deg[i]; }
  if (t == 1023) off[n] = part[1023];
}

// stores SOURCE NODE id per CSR slot
__global__ void k_scatter(const int* __restrict__ dst, const int* __restrict__ src,
                          const int* __restrict__ off,
                          int* __restrict__ cursor, int* __restrict__ slist, int E) {
  int t = blockIdx.x * blockDim.x + threadIdx.x;
  if (t < E) {
    int d = dst[t];
    int p = atomicAdd(&cursor[d], 1);
    slist[off[d] + p] = src[t];
  }
}

// ---------------- converts ----------------
__global__ void k_f2b(const float* __restrict__ x, unsigned short* __restrict__ xb, int n4) {
  int t = blockIdx.x * blockDim.x + threadIdx.x;
  if (t < n4) {
    float4 v = reinterpret_cast<const float4*>(x)[t];
    short4v o;
    o[0] = (short)f2b(v.x); o[1] = (short)f2b(v.y);
    o[2] = (short)f2b(v.z); o[3] = (short)f2b(v.w);
    reinterpret_cast<short4v*>(xb)[t] = o;
  }
}

// W [K,Ncol] f32 -> Wt [Ncol,K] bf16
__global__ __launch_bounds__(256) void k_convT(const float* __restrict__ W,
                                               unsigned short* __restrict__ Wt,
                                               int K, int Ncol) {
  __shared__ float tile[32][33];
  int bx = blockIdx.x * 32;  // Ncol dim
  int by = blockIdx.y * 32;  // K dim
  int tx = threadIdx.x & 31, ty = threadIdx.x >> 5;  // ty 0..7
#pragma unroll
  for (int i = 0; i < 32; i += 8)
    tile[ty + i][tx] = W[(size_t)(by + ty + i) * Ncol + bx + tx];
  __syncthreads();
#pragma unroll
  for (int i = 0; i < 32; i += 8)
    Wt[(size_t)(bx + ty + i) * K + by + tx] = f2b(tile[tx][ty + i]);
}

// assemble concatenated bias vectors in one launch
__global__ void k_bias(const float* __restrict__ b1s, const float* __restrict__ b1d,
                       const float* __restrict__ b1r, const float* __restrict__ b2s,
                       const float* __restrict__ b2d, const float* __restrict__ b2r,
                       float* __restrict__ bias1, float* __restrict__ bias2) {
  int t = blockIdx.x * blockDim.x + threadIdx.x;
  if (t < 1536) {
    bias1[t] = (t < 512) ? b1s[t] : (t < 1024 ? b1d[t - 512] : b1r[t - 1024]);
  } else if (t < 1536 + 3072) {
    int u = t - 1536;
    bias2[u] = (u < 1024) ? b2s[u] : (u < 2048 ? b2d[u - 1024] : b2r[u - 2048]);
  }
}

// ---------------- MFMA GEMM (round-8 proven, unchanged) ----------------
__global__ __launch_bounds__(256) void k_gemm_mfma(const unsigned short* __restrict__ A,
                                                   const unsigned short* __restrict__ Bt,
                                                   const float* __restrict__ bias,
                                                   unsigned short* __restrict__ Cb,
                                                   float* __restrict__ Cf,
                                                   int M, int K, int Ncol, int nbf, int nbn) {
  __shared__ __align__(16) unsigned short lds[24576];  // 48 KB; reused by epilogue
  unsigned short* As = lds;
  unsigned short* Bs = lds + 12288;

  int nwg = gridDim.x;
  int orig = blockIdx.x;
  int xcd = orig & 7, rest = orig >> 3;
  int q = nwg >> 3, r = nwg & 7;
  int base = (xcd < r) ? xcd * (q + 1) : r * (q + 1) + (xcd - r) * q;
  int wgid = base + rest;
  int bm = (wgid / nbn) * 128, bn = (wgid % nbn) * 128;

  int t = threadIdx.x;
  int l = t & 63, w = t >> 6;
  int wr = w >> 1, wc = w & 1;

  f32x4 acc[4][4] = {};

  int srow = t >> 2;
  int scol = ((t & 3) * 8) ^ (((srow >> 1) & 3) << 3);
  int ga0 = bm + srow;       if (ga0 >= M) ga0 = M - 1;
  int ga1 = bm + srow + 64;  if (ga1 >= M) ga1 = M - 1;
  const unsigned short* pA0 = A + (size_t)ga0 * K + scol;
  const unsigned short* pA1 = A + (size_t)ga1 * K + scol;
  const unsigned short* pB0 = Bt + (size_t)(bn + srow) * K + scol;
  const unsigned short* pB1 = Bt + (size_t)(bn + srow + 64) * K + scol;

  int aoff[4], boff[4];
#pragma unroll
  for (int m = 0; m < 4; ++m) {
    int Ra = wr * 64 + m * 16 + (l & 15);
    aoff[m] = Ra * 32 + (((l >> 4) * 8) ^ (((Ra >> 1) & 3) << 3));
    int Rb = wc * 64 + m * 16 + (l & 15);
    boff[m] = Rb * 32 + (((l >> 4) * 8) ^ (((Rb >> 1) & 3) << 3));
  }

  auto stage = [&](int buf, int kofs) {
    unsigned short* Ad = As + buf * 4096;
    unsigned short* Bd = Bs + buf * 4096;
    async_copy16(pA0 + kofs, Ad + t * 8);
    async_copy16(pA1 + kofs, Ad + 2048 + t * 8);
    async_copy16(pB0 + kofs, Bd + t * 8);
    async_copy16(pB1 + kofs, Bd + 2048 + t * 8);
  };

  auto compute = [&](int buf) {
    const unsigned short* Ab = As + buf * 4096;
    const unsigned short* Bb = Bs + buf * 4096;
    short8v af[4], bf[4];
#pragma unroll
    for (int m = 0; m < 4; ++m) af[m] = *reinterpret_cast<const short8v*>(Ab + aoff[m]);
#pragma unroll
    for (int n = 0; n < 4; ++n) bf[n] = *reinterpret_cast<const short8v*>(Bb + boff[n]);
#pragma unroll
    for (int m = 0; m < 4; ++m)
#pragma unroll
      for (int n = 0; n < 4; ++n)
        acc[m][n] = __builtin_amdgcn_mfma_f32_16x16x32_bf16(af[m], bf[n], acc[m][n], 0, 0, 0);
  };

  int nT = K >> 5;
  stage(0, 0);
  stage(1, 32);
  int rd = 0, wr2 = 2;
  for (int tt = 0; tt < nT - 1; ++tt) {
    asm volatile("s_waitcnt vmcnt(4)" ::: "memory");
    __builtin_amdgcn_s_barrier();
    __builtin_amdgcn_sched_barrier(0);
    if (tt + 2 < nT) stage(wr2, (tt + 2) * 32);
    compute(rd);
    rd = (rd == 2) ? 0 : rd + 1;
    wr2 = (wr2 == 2) ? 0 : wr2 + 1;
  }
  asm volatile("s_waitcnt vmcnt(0)" ::: "memory");
  __builtin_amdgcn_s_barrier();
  __builtin_amdgcn_sched_barrier(0);
  compute(rd);

  bool isbf = (bn < nbf);
  if (isbf) {
    __syncthreads();
#pragma unroll
    for (int m = 0; m < 4; ++m)
#pragma unroll
      for (int qq = 0; qq < 4; ++qq) {
        int rr = wr * 64 + m * 16 + (l >> 4) * 4 + qq;
#pragma unroll
        for (int n = 0; n < 4; ++n) {
          int cc = wc * 64 + n * 16 + (l & 15);
          lds[rr * 136 + cc] = f2b(acc[m][n][qq] + bias[bn + cc]);
        }
      }
    __syncthreads();
    int r0 = t >> 4, c0 = (t & 15) * 8;
#pragma unroll
    for (int it = 0; it < 8; ++it) {
      int rr = r0 + it * 16;
      int grow = bm + rr;
      if (grow < M) {
        short8v v = *reinterpret_cast<const short8v*>(lds + rr * 136 + c0);
        *reinterpret_cast<short8v*>(Cb + (size_t)grow * nbf + bn + c0) = v;
      }
    }
  } else {
#pragma unroll
    for (int m = 0; m < 4; ++m) {
#pragma unroll
      for (int qq = 0; qq < 4; ++qq) {
        int row = bm + wr * 64 + m * 16 + (l >> 4) * 4 + qq;
        if (row < M) {
#pragma unroll
          for (int n = 0; n < 4; ++n) {
            int col = bn + wc * 64 + n * 16 + (l & 15);
            Cf[(size_t)row * (Ncol - nbf) + (col - nbf)] = acc[m][n][qq] + bias[col];
          }
        }
      }
    }
  }
}

// ---------------- fused edge phase (round-10 proven, unchanged) ----------------
// f1[N, 3W] bf16: cols [0,W)=fs, [W,2W)=fd, [2W,3W)=res.  attn[H,D] f32.
// One wave per (node, head). Scalar CSR walk: b/e made provably uniform via
// readfirstlane -> slist reads compile to s_load (no index VGPR traffic).
// Two-group software pipeline: 8 gathered rows in flight per wave.
template <int D, bool SUMH>
__global__ __launch_bounds__(256) void k_edge_fused(const unsigned short* __restrict__ f1,
                                                    const float* __restrict__ attn,
                                                    const int* __restrict__ off,
                                                    const int* __restrict__ slist,
                                                    unsigned short* __restrict__ outb,
                                                    int N) {
  constexpr int W = HEADS * D;
  constexpr int W3 = 3 * W;
  constexpr int PER = D / 64;   // elements per lane (4 or 8)
  constexpr int PH = PER / 2;   // f32x2 pairs per lane (2 or 4)
  typedef short rawv __attribute__((ext_vector_type(PER)));
  __shared__ float hs[2][SUMH ? D : 1];

  int w = threadIdx.x >> 6, l = threadIdx.x & 63;
  int node = blockIdx.x * 2 + (w >> 1);
  int h = w & 1;
  bool active = node < N;

  f32x2 fdv[PH], av6[PH], av4[PH], acc2[PH];
  float m = -1e30f, s = 0.f;

  if (active) {
    // wave-uniform scalars, made provable for the compiler
    int hD = __builtin_amdgcn_readfirstlane(h * D);
    int nodeu = __builtin_amdgcn_readfirstlane(node);
    int b = __builtin_amdgcn_readfirstlane(off[nodeu]);
    int e = __builtin_amdgcn_readfirstlane(off[nodeu + 1]);

    const unsigned short* pfd = f1 + (size_t)nodeu * W3 + W + hD + l * PER;
    const float* pa = attn + hD + l * PER;
#pragma unroll
    for (int j = 0; j < PH; ++j) {
      fdv[j] = bpair(reinterpret_cast<const u32*>(pfd)[j]);
      av6[j].x = 0.6f * pa[2 * j]; av6[j].y = 0.6f * pa[2 * j + 1];
      av4[j].x = 0.4f * pa[2 * j]; av4[j].y = 0.4f * pa[2 * j + 1];
      acc2[j].x = 0.f; acc2[j].y = 0.f;
    }

    // fetch group of 4 rows at CSR positions [ii, ii+4) (clamped) into buf
    auto fetch = [&](rawv* buf, int ii) {
#pragma unroll
      for (int j = 0; j < 4; ++j) {
        int jj = ii + j; jj = (jj < e) ? jj : ii;   // scalar clamp
        int sid = slist[jj];                         // s_load (uniform addr)
        buf[j] = *reinterpret_cast<const rawv*>(
            f1 + (size_t)(u32)sid * W3 + hD + l * PER);
      }
    };

    // process group of 4 rows starting at CSR position i
    auto process = [&](const rawv* buf, int i) {
      f32x2 rowf[4][PH];
#pragma unroll
      for (int j = 0; j < 4; ++j) {
        const u32* ru = reinterpret_cast<const u32*>(&buf[j]);
#pragma unroll
        for (int k = 0; k < PH; ++k) rowf[j][k] = bpair(ru[k]);
      }
      float part[4];
#pragma unroll
      for (int j = 0; j < 4; ++j) {
        f32x2 lacc = {0.f, 0.f};
#pragma unroll
        for (int k = 0; k < PH; ++k) {
          f32x2 sv = pk_add(rowf[j][k], fdv[k]);
          f32x2 ab = pk_abs(sv);
          lacc = pk_fma(sv, av6[k], lacc);
          lacc = pk_fma(ab, av4[k], lacc);
        }
        part[j] = lacc.x + lacc.y;
      }
#pragma unroll
      for (int o = 1; o < 64; o <<= 1) {
#pragma unroll
        for (int j = 0; j < 4; ++j) part[j] += __shfl_xor(part[j], o, 64);
      }
#pragma unroll
      for (int j = 0; j < 4; ++j) {
        if (i + j < e) {
          float pj = part[j];
          if (pj <= m) {
            float p = __expf(pj - m);
            s += p;
            f32x2 pp = {p, p};
#pragma unroll
            for (int k = 0; k < PH; ++k) acc2[k] = pk_fma(rowf[j][k], pp, acc2[k]);
          } else {
            float c = (m == -1e30f) ? 0.f : __expf(m - pj);
            s = s * c + 1.f;
            f32x2 cc = {c, c};
#pragma unroll
            for (int k = 0; k < PH; ++k) acc2[k] = pk_fma(acc2[k], cc, rowf[j][k]);
            m = pj;
          }
        }
      }
    };

    if (b < e) {
      rawv A[4], B[4];
      fetch(A, b);
      int i = b;
      while (true) {
        if (i + 4 < e) fetch(B, i + 4);
        process(A, i);
        i += 4;
        if (i >= e) break;
        if (i + 4 < e) fetch(A, i + 4);
        process(B, i);
        i += 4;
        if (i >= e) break;
      }
    }

    float inv = (s > 0.f) ? 1.f / s : 0.f;
    const unsigned short* pr = f1 + (size_t)nodeu * W3 + 2 * W + hD + l * PER;
    f32x2 iv = {inv, inv};
#pragma unroll
    for (int j = 0; j < PH; ++j) {
      f32x2 rr = bpair(reinterpret_cast<const u32*>(pr)[j]);
      f32x2 v = pk_fma(acc2[j], iv, rr);
      v.x = v.x > 0.f ? v.x : 0.f;
      v.y = v.y > 0.f ? v.y : 0.f;
      acc2[j] = v;  // relu'd
    }
  }

  if constexpr (SUMH) {
    if (active && h == 0) {
#pragma unroll
      for (int j = 0; j < PH; ++j) {
        hs[w >> 1][l * PER + 2 * j] = acc2[j].x;
        hs[w >> 1][l * PER + 2 * j + 1] = acc2[j].y;
      }
    }
    __syncthreads();
    if (active && h == 1) {
      short8v o;
#pragma unroll
      for (int j = 0; j < PH; ++j) {
        o[2 * j] = (short)f2b(acc2[j].x + hs[w >> 1][l * PER + 2 * j]);
        o[2 * j + 1] = (short)f2b(acc2[j].y + hs[w >> 1][l * PER + 2 * j + 1]);
      }
      *reinterpret_cast<short8v*>(outb + (size_t)node * D + l * PER) = o;
    }
  } else {
    if (active) {
      short4v o;
#pragma unroll
      for (int j = 0; j < PH; ++j) {
        o[2 * j] = (short)f2b(acc2[j].x);
        o[2 * j + 1] = (short)f2b(acc2[j].y);
      }
      *reinterpret_cast<short4v*>(outb + (size_t)node * W + h * D + l * PER) = o;
    }
  }
}

extern "C" void kernel_launch(void* const* d_in, const int* in_sizes, int n_in,
                              void* d_out, int out_size, void* d_ws, size_t ws_size,
                              hipStream_t stream) {
  const float* x    = (const float*)d_in[0];
  const int*   src  = (const int*)d_in[1];
  const int*   dst  = (const int*)d_in[2];
  const float* W1s  = (const float*)d_in[3];
  const float* b1s  = (const float*)d_in[4];
  const float* W1d  = (const float*)d_in[5];
  const float* b1d  = (const float*)d_in[6];
  const float* at1  = (const float*)d_in[7];
  const float* W1r  = (const float*)d_in[8];
  const float* b1r  = (const float*)d_in[9];
  const float* W2s  = (const float*)d_in[10];
  const float* b2s  = (const float*)d_in[11];
  const float* W2d  = (const float*)d_in[12];
  const float* b2d  = (const float*)d_in[13];
  const float* at2  = (const float*)d_in[14];
  const float* W2r  = (const float*)d_in[15];
  const float* b2r  = (const float*)d_in[16];
  const float* Wp   = (const float*)d_in[17];
  const float* bp   = (const float*)d_in[18];
  float* out = (float*)d_out;

  const int N = in_sizes[0] / 1024;  // 10000
  const int E = in_sizes[1];         // 160000

  // ---- workspace layout ----
  char* ws = (char*)d_ws;
  size_t o = 0;
  auto alloc = [&](size_t bytes) { char* p = ws + o; o += (bytes + 255) & ~(size_t)255; return p; };
  unsigned short* xb    = (unsigned short*)alloc((size_t)N * 1024 * 2);
  unsigned short* w1cat = (unsigned short*)alloc((size_t)1536 * 1024 * 2);
  unsigned short* w2cat = (unsigned short*)alloc((size_t)3072 * 512 * 2);
  unsigned short* wp    = (unsigned short*)alloc((size_t)512 * 512 * 2);
  float*          bias1 = (float*)alloc(1536 * 4);
  float*          bias2 = (float*)alloc(3072 * 4);
  unsigned short* f1    = (unsigned short*)alloc((size_t)N * 3072 * 2);  // fs||fd||res
  unsigned short* h1    = (unsigned short*)alloc((size_t)N * 512 * 2);
  unsigned short* h2    = (unsigned short*)alloc((size_t)N * 512 * 2);
  int* deg    = (int*)alloc((size_t)N * 4);
  int* cursor = (int*)alloc((size_t)N * 4);
  int* offp   = (int*)alloc((size_t)(N + 1) * 4);
  int* slist  = (int*)alloc((size_t)E * 4);
  if (o > ws_size) return;

  // ---- CSR build ----
  size_t zlen = (size_t)((char*)(cursor + N) - (char*)deg);
  hipMemsetAsync(deg, 0, zlen, stream);
  k_count<<<(E + 255) / 256, 256, 0, stream>>>(dst, deg, E);
  k_scan<<<1, 1024, 0, stream>>>(deg, offp, N);
  k_scatter<<<(E + 255) / 256, 256, 0, stream>>>(dst, src, offp, cursor, slist, E);

  // ---- converts ----
  k_f2b<<<((N * 1024 / 4) + 255) / 256, 256, 0, stream>>>(x, xb, N * 1024 / 4);
  {
    dim3 gT1(512 / 32, 1024 / 32);
    k_convT<<<gT1, 256, 0, stream>>>(W1s, w1cat + (size_t)0 * 1024, 1024, 512);
    k_convT<<<gT1, 256, 0, stream>>>(W1d, w1cat + (size_t)512 * 1024, 1024, 512);
    k_convT<<<gT1, 256, 0, stream>>>(W1r, w1cat + (size_t)1024 * 1024, 1024, 512);
    dim3 gT2(1024 / 32, 512 / 32);
    k_convT<<<gT2, 256, 0, stream>>>(W2s, w2cat + (size_t)0 * 512, 512, 1024);
    k_convT<<<gT2, 256, 0, stream>>>(W2d, w2cat + (size_t)1024 * 512, 512, 1024);
    k_convT<<<gT2, 256, 0, stream>>>(W2r, w2cat + (size_t)2048 * 512, 512, 1024);
    dim3 gT3(512 / 32, 512 / 32);
    k_convT<<<gT3, 256, 0, stream>>>(Wp, wp, 512, 512);
  }
  k_bias<<<(1536 + 3072 + 255) / 256, 256, 0, stream>>>(b1s, b1d, b1r, b2s, b2d, b2r,
                                                        bias1, bias2);

  int nbm = (N + 127) / 128;  // 79

  // ---- conv1: [N,1024] @ [1024,1536] -> f1[N,1536] bf16 (fs|fd|res) ----
  k_gemm_mfma<<<nbm * (1536 / 128), 256, 0, stream>>>(xb, w1cat, bias1, f1, nullptr,
                                                      N, 1024, 1536, 1536, 1536 / 128);
  k_edge_fused<256, false><<<(N + 1) / 2, 256, 0, stream>>>(f1, at1, offp, slist, h1, N);

  // ---- conv2: [N,512] @ [512,3072] -> f1[N,3072] bf16 (fs|fd|res) ----
  k_gemm_mfma<<<nbm * (3072 / 128), 256, 0, stream>>>(h1, w2cat, bias2, f1, nullptr,
                                                      N, 512, 3072, 3072, 3072 / 128);
  k_edge_fused<512, true><<<(N + 1) / 2, 256, 0, stream>>>(f1, at2, offp, slist, h2, N);

  // ---- projection: h2[N,512] @ [512,512] -> out f32 (final relu no-op) ----
  k_gemm_mfma<<<nbm * (512 / 128), 256, 0, stream>>>(h2, wp, bp, nullptr, out,
                                                     N, 512, 512, 0, 512 / 128);
}